// Round 11
// baseline (394.632 us; speedup 1.0000x reference)
//
#include <hip/hip_runtime.h>
#include <cstdint>
#include <cstddef>

// N=4, L=2048, E=1024, H=16, D=64.  Token rows M = N*L = 8192.
// Pipeline: weight-only cvt fp32->bf16 (4 MB), fused QKV projection GEMM
// reading ACTIVATIONS DIRECTLY AS FP32 (in-staging cvt_pk conversion for
// one operand per sub-GEMM; single-buffered LDS, 4 blk/CU, chunked-XCD
// remap), no-max flash attention (R8 best: 4 waves, in-register P via
// swapped QK^T + permlane swaps, double-buffered K/V, XCD-local heads,
// ones-MFMA row-sum, zero-C QK^T), output GEMM (fp32 out).

typedef __bf16 bf16x8 __attribute__((ext_vector_type(8)));
typedef __bf16 bf16x4 __attribute__((ext_vector_type(4)));
typedef __bf16 bf16x2 __attribute__((ext_vector_type(2)));
typedef float f32x4 __attribute__((ext_vector_type(4)));
typedef float f32x2 __attribute__((ext_vector_type(2)));
typedef unsigned int uint2v __attribute__((ext_vector_type(2)));
typedef unsigned int uint4v __attribute__((ext_vector_type(4)));

#define LOG2E_OVER_SQRTD 0.18033688011112042f  // log2(e)/8, folded into q

__device__ __forceinline__ unsigned short f2bf(float f) {
  unsigned int u = __builtin_bit_cast(unsigned int, f);
  u = (u + 0x7fffu + ((u >> 16) & 1u)) >> 16;  // RNE
  return (unsigned short)u;
}

__device__ __forceinline__ unsigned int pk2(float a, float b) {
  f32x2 t = {a, b};
  bf16x2 h = __builtin_convertvector(t, bf16x2);  // v_cvt_pk_bf16_f32 (RNE)
  return __builtin_bit_cast(unsigned int, h);
}

// async 16B global->LDS
__device__ __forceinline__ void gl2lds16(const void* g, void* l) {
  __builtin_amdgcn_global_load_lds(
      (__attribute__((address_space(1))) unsigned int*)g,
      (__attribute__((address_space(3))) unsigned int*)l, 16, 0, 0);
}

// softmax half-tile: S^T frags (two 16-row key blocks) -> PV A-fragment.
// lane (g'=lg, q=lr) holds P^T[k][q]; permlane32+permlane16 swaps
// redistribute packed bf16 pairs into A-frag order (keys 8g..8g+7).
__device__ __forceinline__ bf16x8 mk_ap(f32x4 sA, f32x4 sB) {
  float peA[4], peB[4];
#pragma unroll
  for (int r = 0; r < 4; ++r) {
    peA[r] = __builtin_amdgcn_exp2f(sA[r]);
    peB[r] = __builtin_amdgcn_exp2f(sB[r]);
  }
  unsigned int x00 = pk2(peA[0], peA[1]);
  unsigned int x01 = pk2(peA[2], peA[3]);
  unsigned int x10 = pk2(peB[0], peB[1]);
  unsigned int x11 = pk2(peB[2], peB[3]);
  uint2v s0 = __builtin_amdgcn_permlane32_swap(x00, x10, false, false);
  uint2v t0 = __builtin_amdgcn_permlane16_swap(s0[0], s0[1], false, false);
  uint2v s1 = __builtin_amdgcn_permlane32_swap(x01, x11, false, false);
  uint2v t1 = __builtin_amdgcn_permlane16_swap(s1[0], s1[1], false, false);
  uint4v u;
  u[0] = t0[0];  // k 8g+0,1
  u[1] = t1[0];  // k 8g+2,3
  u[2] = t0[1];  // k 8g+4,5
  u[3] = t1[1];  // k 8g+6,7
  return __builtin_bit_cast(bf16x8, u);
}

// ---------------------------------------------------------------- cvt kernel
// Weights only now: 4 x [1024x1024].  Grid (1024, 4).
struct CvtArgs {
  const float* src[4];
  unsigned short* dst[4];
};
__global__ __launch_bounds__(256) void cvt_w_k(CvtArgs a) {
  const float* s = a.src[blockIdx.y];
  unsigned short* d = a.dst[blockIdx.y];
  size_t i = ((size_t)blockIdx.x * 256 + threadIdx.x) * 4;
  float4 v = *(const float4*)(s + i);
  ushort4 o;
  o.x = f2bf(v.x); o.y = f2bf(v.y); o.z = f2bf(v.z); o.w = f2bf(v.w);
  *(ushort4*)(d + i) = o;
}

// ---------------------------------------------------------------- GEMM
// C[M][N] = A[M][1024] @ Bt[N][1024]^T, fp32-or-bf16 in, fp32 acc.
// 128x128 tile, BK=64 (16 K-iters), 4 waves each 64x64, single-buffered
// LDS (32 KB -> 4 blocks/CU at VGPR<=128).  Per-descriptor a_f32/b_f32:
// that operand is read as fp32 from global, converted with cvt_pk in
// registers, and ds_write_b128'd to the SAME swizzled LDS slots the
// gl2lds16 path uses (replaces the separate activation-cvt kernel).
// Chunked-XCD remap (nbx_shift==3): 8 contiguous by per XCD (A L2-local).
struct GemmDesc {
  const unsigned short* A;
  const unsigned short* Bt;
  const float* bias;
  void* C;
  int N;          // C column count / row stride
  int nbx_shift;  // log2(N/128)
  float scale;
  int bias_row;   // bias indexed by row instead of col
  int permc;      // store cols permuted: col' = 4*(col&15) + ((col>>4)&3)
  int a_f32;      // A operand is fp32 in global (convert in staging)
  int b_f32;      // Bt operand is fp32 in global
};
struct GemmPack3 {
  GemmDesc g[3];
};

template <bool OUT_F32>
__global__ __launch_bounds__(256, 4) void gemm_multi_k(GemmPack3 p) {
  __shared__ __attribute__((aligned(16))) unsigned short As[128 * 64];
  __shared__ __attribute__((aligned(16))) unsigned short Bs[128 * 64];
  const GemmDesc d = p.g[blockIdx.x >> 9];
  int t = blockIdx.x & 511;
  if (d.nbx_shift == 3) t = ((t & 7) << 6) | (t >> 3);  // chunked XCD remap
  const int bx = t & ((1 << d.nbx_shift) - 1);
  const int by = t >> d.nbx_shift;

  const int tid = threadIdx.x;
  const int lane = tid & 63, wave = tid >> 6;
  const int lr = lane & 15, lg = lane >> 4;
  const int rowBase = by * 128;
  const int colBase = bx * 128;
  const int wm = (wave & 1) * 64, wn = (wave >> 1) * 64;

  f32x4 acc[4][4] = {};

  // staging: 4 slots/thread/matrix; slot s -> row=s>>3, seg t=s&7,
  // global chunk c = t ^ (row&7)  (reader swizzle matches)
  const unsigned short* gA[4];
  const float* gAf[4];
  const unsigned short* gB[4];
  const float* gBf[4];
  unsigned short* lA[4];
  unsigned short* lB[4];
#pragma unroll
  for (int i = 0; i < 4; ++i) {
    int s = tid + i * 256;
    int row = s >> 3;
    int c = (s & 7) ^ (row & 7);
    size_t offA = (size_t)(rowBase + row) * 1024 + c * 8;
    size_t offB = (size_t)(colBase + row) * 1024 + c * 8;
    gA[i] = d.A + offA;
    gAf[i] = (const float*)(const void*)d.A + offA;
    gB[i] = d.Bt + offB;
    gBf[i] = (const float*)(const void*)d.Bt + offB;
    lA[i] = &As[s * 8];
    lB[i] = &Bs[s * 8];
  }

  for (int kt = 0; kt < 16; ++kt) {
    const int ko = kt * 64;
    if (d.a_f32) {
#pragma unroll
      for (int i = 0; i < 4; ++i) {
        float4 a0 = *(const float4*)(gAf[i] + ko);
        float4 a1 = *(const float4*)(gAf[i] + ko + 4);
        uint4v u;
        u[0] = pk2(a0.x, a0.y);
        u[1] = pk2(a0.z, a0.w);
        u[2] = pk2(a1.x, a1.y);
        u[3] = pk2(a1.z, a1.w);
        *(uint4v*)lA[i] = u;
      }
    } else {
#pragma unroll
      for (int i = 0; i < 4; ++i) gl2lds16(gA[i] + ko, lA[i]);
    }
    if (d.b_f32) {
#pragma unroll
      for (int i = 0; i < 4; ++i) {
        float4 b0 = *(const float4*)(gBf[i] + ko);
        float4 b1 = *(const float4*)(gBf[i] + ko + 4);
        uint4v u;
        u[0] = pk2(b0.x, b0.y);
        u[1] = pk2(b0.z, b0.w);
        u[2] = pk2(b1.x, b1.y);
        u[3] = pk2(b1.z, b1.w);
        *(uint4v*)lB[i] = u;
      }
    } else {
#pragma unroll
      for (int i = 0; i < 4; ++i) gl2lds16(gB[i] + ko, lB[i]);
    }
    __syncthreads();  // staging (async + ds_write) complete

#pragma unroll
    for (int ks = 0; ks < 2; ++ks) {
      bf16x8 af[4], bfr[4];
#pragma unroll
      for (int mt = 0; mt < 4; ++mt) {
        int row = wm + mt * 16 + lr;
        int c = (ks * 4 + lg) ^ (row & 7);
        af[mt] = *(const bf16x8*)&As[row * 64 + c * 8];
      }
#pragma unroll
      for (int nt = 0; nt < 4; ++nt) {
        int row = wn + nt * 16 + lr;
        int c = (ks * 4 + lg) ^ (row & 7);
        bfr[nt] = *(const bf16x8*)&Bs[row * 64 + c * 8];
      }
#pragma unroll
      for (int mt = 0; mt < 4; ++mt)
#pragma unroll
        for (int nt = 0; nt < 4; ++nt)
          acc[mt][nt] = __builtin_amdgcn_mfma_f32_16x16x32_bf16(
              af[mt], bfr[nt], acc[mt][nt], 0, 0, 0);
    }
    __syncthreads();  // waves done reading before restage
  }

  // epilogue: C-layout col=lane&15, row=(lane>>4)*4+reg
#pragma unroll
  for (int mt = 0; mt < 4; ++mt)
#pragma unroll
    for (int nt = 0; nt < 4; ++nt) {
      int col = colBase + wn + nt * 16 + lr;
      int colStore = d.permc ? (colBase + wn + lr * 4 + nt) : col;
      float bcol = d.bias_row ? 0.f : d.bias[col];
#pragma unroll
      for (int r = 0; r < 4; ++r) {
        int row = rowBase + wm + mt * 16 + lg * 4 + r;
        float b = d.bias_row ? d.bias[row] : bcol;
        float val = (acc[mt][nt][r] + b) * d.scale;
        size_t idx = (size_t)row * (size_t)d.N + (size_t)colStore;
        if (OUT_F32)
          ((float*)d.C)[idx] = val;
        else
          ((unsigned short*)d.C)[idx] = f2bf(val);
      }
    }
}

// ---------------------------------------------------------------- attention
// (round-8 best: 78.5 us, no spill)  One block per (n, h, 128-row q-tile).
// 4 waves x 32 q-rows.  KT=64.  XCD-local placement: all 16 q-tiles of one
// (n,h) land on the SAME XCD -> K/V panels L2-resident.  Register-lean
// half-tile pipeline: K-frags read per half and released; S0 -> S1(issue)
// -> bv0 reads -> softmax(S0) [overlaps S1 exec + bv0 latency] -> PV0 ->
// bv1 reads -> softmax(S1) [overlaps PV0] -> PV1.
__global__ __launch_bounds__(256, 4) void attn_k(
    const unsigned short* __restrict__ qb,   // [8192][1024]
    const unsigned short* __restrict__ kb,   // [8192][1024]
    const unsigned short* __restrict__ vtb,  // [1024][8192] natural key order
    unsigned short* __restrict__ aob) {      // [8192][1024]
  __shared__ __attribute__((aligned(16))) unsigned short Ks[2 * 64 * 64];
  __shared__ __attribute__((aligned(16))) unsigned short Vts[2 * 64 * 64];

  const int tid = threadIdx.x;
  const int lane = tid & 63, wave = tid >> 6;
  const int lr = lane & 15, lg = lane >> 4;

  // XCD-local swizzle: xcd = bid&7 (dispatch round-robin), 16 q-tiles of
  // each nh stay on one XCD.  Bijective: nh = (idx>>4)*8 + xcd in [0,64).
  const int bid = blockIdx.x;
  const int xcd = bid & 7;
  const int idx = bid >> 3;
  const int qt = idx & 15;
  const int nh = (idx >> 4) * 8 + xcd;
  const int h = nh & 15, n = nh >> 4;
  const int q0 = qt * 128;

  // ---- stage Q tile (128x64 = 16KB) overlaying both K buffers
#pragma unroll
  for (int i = 0; i < 4; ++i) {
    int s = i * 256 + tid;
    int row = s >> 3;
    int c = (s & 7) ^ (row & 7);
    gl2lds16(qb + (((size_t)n * 2048 + q0 + row) << 10) + h * 64 + c * 8,
             &Ks[s * 8]);
  }
  __syncthreads();

  bf16x8 aq[2][2];
#pragma unroll
  for (int mt = 0; mt < 2; ++mt)
#pragma unroll
    for (int ks = 0; ks < 2; ++ks) {
      int row = wave * 32 + mt * 16 + lr;
      int c = (ks * 4 + lg) ^ (row & 7);
      aq[mt][ks] = *(const bf16x8*)&Ks[row * 64 + c * 8];
    }
  __syncthreads();  // Q reads done; Ks becomes K double-buffer

  // per-lane LDS read bases: index = nt*1024 + lr*64 + c(ks)*8 (+cb)
  const int a0 = lr * 64 + ((lg ^ (lr & 7)) * 8);
  const int a1 = lr * 64 + (((4 + lg) ^ (lr & 7)) * 8);
  const unsigned short* Kb0 = &Ks[a0];
  const unsigned short* Kb1 = &Ks[a1];
  const unsigned short* Vb0 = &Vts[a0];
  const unsigned short* Vb1 = &Vts[a1];

  // staging addresses fixed per thread; advance by one tile per iteration
  const unsigned short* kg[2];
  const unsigned short* vg[2];
  int ldo[2];
#pragma unroll
  for (int i = 0; i < 2; ++i) {
    int s = i * 256 + tid;
    int row = s >> 3;
    int c = (s & 7) ^ (row & 7);
    kg[i] = kb + (((size_t)n * 2048 + row) << 10) + h * 64 + c * 8;
    vg[i] = vtb + (((size_t)(h * 64 + row)) << 13) + (size_t)n * 2048 + c * 8;
    ldo[i] = s * 8;
  }
  // stage k-tile 0 into buffer 0
#pragma unroll
  for (int i = 0; i < 2; ++i) {
    gl2lds16(kg[i], &Ks[ldo[i]]);
    gl2lds16(vg[i], &Vts[ldo[i]]);
    kg[i] += 64 * 1024;
    vg[i] += 64;
  }

  bf16x8 ones;
#pragma unroll
  for (int i = 0; i < 8; ++i) ones[i] = (__bf16)1.0f;
  const f32x4 fzero = {0.f, 0.f, 0.f, 0.f};

  f32x4 o_acc[2][4] = {};
  f32x4 o_sum[2] = {};

#pragma unroll 2
  for (int kt = 0; kt < 32; ++kt) {
    const int cb = (kt & 1) * 4096;  // current buffer base (shorts)
    const int nb = 4096 - cb;        // next buffer base
    __syncthreads();  // buf[cur] staged; prior reads of buf[next] complete

    if (kt < 31) {  // prefetch next tile before compute (loads overlap MFMA)
#pragma unroll
      for (int i = 0; i < 2; ++i) {
        gl2lds16(kg[i], &Ks[nb + ldo[i]]);
        gl2lds16(vg[i], &Vts[nb + ldo[i]]);
        kg[i] += 64 * 1024;
        vg[i] += 64;
      }
    }

    f32x4 sA[2][2], sB[2][2];
    // S half0: keys 0..31; K-frags scoped so regs release after use
    {
      bf16x8 k00 = *(const bf16x8*)(Kb0 + cb);
      bf16x8 k10 = *(const bf16x8*)(Kb1 + cb);
      bf16x8 k01 = *(const bf16x8*)(Kb0 + cb + 1024);
      bf16x8 k11 = *(const bf16x8*)(Kb1 + cb + 1024);
      __builtin_amdgcn_s_setprio(1);
#pragma unroll
      for (int mt = 0; mt < 2; ++mt) {
        f32x4 t0 = __builtin_amdgcn_mfma_f32_16x16x32_bf16(
            k00, aq[mt][0], fzero, 0, 0, 0);
        sA[mt][0] = __builtin_amdgcn_mfma_f32_16x16x32_bf16(
            k10, aq[mt][1], t0, 0, 0, 0);
        f32x4 t1 = __builtin_amdgcn_mfma_f32_16x16x32_bf16(
            k01, aq[mt][0], fzero, 0, 0, 0);
        sA[mt][1] = __builtin_amdgcn_mfma_f32_16x16x32_bf16(
            k11, aq[mt][1], t1, 0, 0, 0);
      }
      __builtin_amdgcn_s_setprio(0);
    }
    // S half1: keys 32..63
    {
      bf16x8 k02 = *(const bf16x8*)(Kb0 + cb + 2048);
      bf16x8 k12 = *(const bf16x8*)(Kb1 + cb + 2048);
      bf16x8 k03 = *(const bf16x8*)(Kb0 + cb + 3072);
      bf16x8 k13 = *(const bf16x8*)(Kb1 + cb + 3072);
      __builtin_amdgcn_s_setprio(1);
#pragma unroll
      for (int mt = 0; mt < 2; ++mt) {
        f32x4 t0 = __builtin_amdgcn_mfma_f32_16x16x32_bf16(
            k02, aq[mt][0], fzero, 0, 0, 0);
        sB[mt][0] = __builtin_amdgcn_mfma_f32_16x16x32_bf16(
            k12, aq[mt][1], t0, 0, 0, 0);
        f32x4 t1 = __builtin_amdgcn_mfma_f32_16x16x32_bf16(
            k03, aq[mt][0], fzero, 0, 0, 0);
        sB[mt][1] = __builtin_amdgcn_mfma_f32_16x16x32_bf16(
            k13, aq[mt][1], t1, 0, 0, 0);
      }
      __builtin_amdgcn_s_setprio(0);
    }

    // V half0 reads (keys 0..31; latency hides under softmax half0)
    {
      bf16x8 bv0[4];
#pragma unroll
      for (int nt = 0; nt < 4; ++nt)
        bv0[nt] = *(const bf16x8*)(Vb0 + cb + nt * 1024);

      // softmax half0 (VALU; overlaps S-half1 MFMA exec + bv0 ds latency)
      bf16x8 ap0[2];
#pragma unroll
      for (int mt = 0; mt < 2; ++mt) ap0[mt] = mk_ap(sA[mt][0], sA[mt][1]);

      // PV half0 + row-sum
      __builtin_amdgcn_s_setprio(1);
#pragma unroll
      for (int mt = 0; mt < 2; ++mt) {
        o_sum[mt] = __builtin_amdgcn_mfma_f32_16x16x32_bf16(
            ap0[mt], ones, o_sum[mt], 0, 0, 0);
#pragma unroll
        for (int nt = 0; nt < 4; ++nt)
          o_acc[mt][nt] = __builtin_amdgcn_mfma_f32_16x16x32_bf16(
              ap0[mt], bv0[nt], o_acc[mt][nt], 0, 0, 0);
      }
      __builtin_amdgcn_s_setprio(0);
    }

    // V half1 reads + softmax half1 (overlaps PV half0 exec)
    {
      bf16x8 bv1[4];
#pragma unroll
      for (int nt = 0; nt < 4; ++nt)
        bv1[nt] = *(const bf16x8*)(Vb1 + cb + nt * 1024);

      bf16x8 ap1[2];
#pragma unroll
      for (int mt = 0; mt < 2; ++mt) ap1[mt] = mk_ap(sB[mt][0], sB[mt][1]);

      // PV half1 + row-sum
      __builtin_amdgcn_s_setprio(1);
#pragma unroll
      for (int mt = 0; mt < 2; ++mt) {
        o_sum[mt] = __builtin_amdgcn_mfma_f32_16x16x32_bf16(
            ap1[mt], ones, o_sum[mt], 0, 0, 0);
#pragma unroll
        for (int nt = 0; nt < 4; ++nt)
          o_acc[mt][nt] = __builtin_amdgcn_mfma_f32_16x16x32_bf16(
              ap1[mt], bv1[nt], o_acc[mt][nt], 0, 0, 0);
      }
      __builtin_amdgcn_s_setprio(0);
    }
  }

  // epilogue: O C-layout col=d=lane&15, row=q=(lane>>4)*4+r.
  // o_sum[mt][r] is the full row-sum for this lane's O-row already.
#pragma unroll
  for (int mt = 0; mt < 2; ++mt) {
#pragma unroll
    for (int r = 0; r < 4; ++r) {
      float inv = 1.0f / o_sum[mt][r];
      int row_l = q0 + wave * 32 + mt * 16 + lg * 4 + r;
      size_t base = (((size_t)n * 2048 + row_l) << 10) + h * 64;
#pragma unroll
      for (int nt = 0; nt < 4; ++nt)
        aob[base + nt * 16 + lr] = f2bf(o_acc[mt][nt][r] * inv);
    }
  }
}

// ---------------------------------------------------------------- launch
extern "C" void kernel_launch(void* const* d_in, const int* in_sizes, int n_in,
                              void* d_out, int out_size, void* d_ws,
                              size_t ws_size, hipStream_t stream) {
  const float* Q = (const float*)d_in[0];
  const float* K = (const float*)d_in[1];
  const float* V = (const float*)d_in[2];
  const float* Wq = (const float*)d_in[3];
  const float* bq = (const float*)d_in[4];
  const float* Wk = (const float*)d_in[5];
  const float* bk = (const float*)d_in[6];
  const float* Wv = (const float*)d_in[7];
  const float* bv = (const float*)d_in[8];
  const float* Wo = (const float*)d_in[9];
  const float* bo = (const float*)d_in[10];

  const size_t S = (size_t)8192 * 1024;
  const size_t W = (size_t)1024 * 1024;
  unsigned short* ws = (unsigned short*)d_ws;
  unsigned short* aob = ws;  // attention output (bf16)
  unsigned short* qbuf = ws + 3 * S;
  unsigned short* kbuf = ws + 4 * S;
  unsigned short* vtbuf = ws + 5 * S;
  unsigned short* Wqb = ws + 6 * S;
  unsigned short* Wkb = Wqb + W;
  unsigned short* Wvb = Wqb + 2 * W;
  unsigned short* Wob = Wqb + 3 * W;

  CvtArgs cw;
  cw.src[0] = Wq; cw.dst[0] = Wqb;
  cw.src[1] = Wk; cw.dst[1] = Wkb;
  cw.src[2] = Wv; cw.dst[2] = Wvb;
  cw.src[3] = Wo; cw.dst[3] = Wob;
  cvt_w_k<<<dim3(1024, 4), 256, 0, stream>>>(cw);

  // fused QKV projections (activations read as fp32, converted in staging):
  //   g0: q = (Q Wq^T + bq)*log2e/8            [8192x1024]  (A fp32)
  //   g1: k =  K Wk^T + bk                     [8192x1024]  (A fp32)
  //   g2: v^T = Wvb V^T + bv (natural order)   [1024x8192]  (B fp32)
  GemmPack3 pp;
  pp.g[0] = {(const unsigned short*)(const void*)Q, Wqb, bq, qbuf,
             1024, 3, LOG2E_OVER_SQRTD, 0, 0, 1, 0};
  pp.g[1] = {(const unsigned short*)(const void*)K, Wkb, bk, kbuf,
             1024, 3, 1.0f, 0, 0, 1, 0};
  pp.g[2] = {Wvb, (const unsigned short*)(const void*)V, bv, vtbuf,
             8192, 6, 1.0f, 1, 0, 0, 1};
  gemm_multi_k<false><<<1536, 256, 0, stream>>>(pp);

  attn_k<<<1024, 256, 0, stream>>>(qbuf, kbuf, vtbuf, aob);

  // out = AO Wo^T + bo  (fp32; both operands bf16 -> gl2lds path)
  GemmPack3 po;
  po.g[0] = {aob, Wob, bo, d_out, 1024, 3, 1.0f, 0, 0, 0, 0};
  po.g[1] = po.g[0];
  po.g[2] = po.g[0];
  gemm_multi_k<true><<<512, 256, 0, stream>>>(po);
}

// Round 12
// 380.607 us; speedup vs baseline: 1.0368x; 1.0368x over previous
//
#include <hip/hip_runtime.h>
#include <cstdint>
#include <cstddef>

// N=4, L=2048, E=1024, H=16, D=64.  Token rows M = N*L = 8192.
// Pipeline: weight-only cvt fp32->bf16 (4 MB), fused QKV projection GEMM
// with T14 async-STAGE split (fp32 activations reg-staged with cvt_pk,
// loads issued at compute start and drained after compute; bf16 operand
// via gl2lds double-buffer; 48KB LDS, 3 blk/CU), no-max flash attention
// (R8 best), output GEMM (fp32 out, same T14 structure, bf16 reg copy).

typedef __bf16 bf16x8 __attribute__((ext_vector_type(8)));
typedef __bf16 bf16x4 __attribute__((ext_vector_type(4)));
typedef __bf16 bf16x2 __attribute__((ext_vector_type(2)));
typedef float f32x4 __attribute__((ext_vector_type(4)));
typedef float f32x2 __attribute__((ext_vector_type(2)));
typedef unsigned int uint2v __attribute__((ext_vector_type(2)));
typedef unsigned int uint4v __attribute__((ext_vector_type(4)));

#define LOG2E_OVER_SQRTD 0.18033688011112042f  // log2(e)/8, folded into q

__device__ __forceinline__ unsigned short f2bf(float f) {
  unsigned int u = __builtin_bit_cast(unsigned int, f);
  u = (u + 0x7fffu + ((u >> 16) & 1u)) >> 16;  // RNE
  return (unsigned short)u;
}

__device__ __forceinline__ unsigned int pk2(float a, float b) {
  f32x2 t = {a, b};
  bf16x2 h = __builtin_convertvector(t, bf16x2);  // v_cvt_pk_bf16_f32 (RNE)
  return __builtin_bit_cast(unsigned int, h);
}

// async 16B global->LDS
__device__ __forceinline__ void gl2lds16(const void* g, void* l) {
  __builtin_amdgcn_global_load_lds(
      (__attribute__((address_space(1))) unsigned int*)g,
      (__attribute__((address_space(3))) unsigned int*)l, 16, 0, 0);
}

// softmax half-tile: S^T frags (two 16-row key blocks) -> PV A-fragment.
__device__ __forceinline__ bf16x8 mk_ap(f32x4 sA, f32x4 sB) {
  float peA[4], peB[4];
#pragma unroll
  for (int r = 0; r < 4; ++r) {
    peA[r] = __builtin_amdgcn_exp2f(sA[r]);
    peB[r] = __builtin_amdgcn_exp2f(sB[r]);
  }
  unsigned int x00 = pk2(peA[0], peA[1]);
  unsigned int x01 = pk2(peA[2], peA[3]);
  unsigned int x10 = pk2(peB[0], peB[1]);
  unsigned int x11 = pk2(peB[2], peB[3]);
  uint2v s0 = __builtin_amdgcn_permlane32_swap(x00, x10, false, false);
  uint2v t0 = __builtin_amdgcn_permlane16_swap(s0[0], s0[1], false, false);
  uint2v s1 = __builtin_amdgcn_permlane32_swap(x01, x11, false, false);
  uint2v t1 = __builtin_amdgcn_permlane16_swap(s1[0], s1[1], false, false);
  uint4v u;
  u[0] = t0[0];  // k 8g+0,1
  u[1] = t1[0];  // k 8g+2,3
  u[2] = t0[1];  // k 8g+4,5
  u[3] = t1[1];  // k 8g+6,7
  return __builtin_bit_cast(bf16x8, u);
}

// ---------------------------------------------------------------- cvt kernel
// Weights only: 4 x [1024x1024].  Grid (1024, 4).
struct CvtArgs {
  const float* src[4];
  unsigned short* dst[4];
};
__global__ __launch_bounds__(256) void cvt_w_k(CvtArgs a) {
  const float* s = a.src[blockIdx.y];
  unsigned short* d = a.dst[blockIdx.y];
  size_t i = ((size_t)blockIdx.x * 256 + threadIdx.x) * 4;
  float4 v = *(const float4*)(s + i);
  ushort4 o;
  o.x = f2bf(v.x); o.y = f2bf(v.y); o.z = f2bf(v.z); o.w = f2bf(v.w);
  *(ushort4*)(d + i) = o;
}

// ---------------------------------------------------------------- GEMM
// C[M][N] = A[M][1024] @ Bt[N][1024]^T, fp32/bf16 in, fp32 acc.
// 128x128 tile, BK=64, 4 waves.  T14 async-STAGE split:
//   REG operand (the fp32 one, or A as bf16 copy): global->regs issued at
//     compute start; cvt_pk + ds_write_b128 into single 16KB LDS tile
//     after barrier#1 (reads of prior tile done).  Load latency hides
//     under the previous compute phase.
//   ASYNC operand: gl2lds into 32KB double buffer, issued at compute
//     start, drained at the post-compute barrier (cheap).
// 48KB LDS -> 3 blk/CU at (256,3).  Chunked-XCD remap (nbx_shift==3).
// Staging/swizzle indexing identical to the R11-verified version.
struct GemmDesc {
  const void* A;
  const void* Bt;
  const float* bias;
  void* C;
  int N;          // C column count / row stride
  int nbx_shift;  // log2(N/128)
  float scale;
  int bias_row;   // bias indexed by row instead of col
  int permc;      // store cols permuted (unused now, kept for layout)
  int reg_is_b;   // reg-staged operand is Bt (else A)
  int reg_f32;    // reg-staged operand is fp32 (else bf16 copy)
};
struct GemmPack3 {
  GemmDesc g[3];
};

template <bool OUT_F32>
__global__ __launch_bounds__(256, 3) void gemm_multi_k(GemmPack3 p) {
  __shared__ __attribute__((aligned(16))) unsigned short Rs[128 * 64];
  __shared__ __attribute__((aligned(16))) unsigned short Ds[2 * 128 * 64];
  const GemmDesc d = p.g[blockIdx.x >> 9];
  int t = blockIdx.x & 511;
  if (d.nbx_shift == 3) t = ((t & 7) << 6) | (t >> 3);  // chunked XCD remap
  const int bx = t & ((1 << d.nbx_shift) - 1);
  const int by = t >> d.nbx_shift;

  const int tid = threadIdx.x;
  const int lane = tid & 63, wave = tid >> 6;
  const int lr = lane & 15, lg = lane >> 4;
  const int rowBase = by * 128;
  const int colBase = bx * 128;
  const int wm = (wave & 1) * 64, wn = (wave >> 1) * 64;

  f32x4 acc[4][4] = {};

  // staging: 4 slots/thread/operand; slot s -> row=s>>3, seg=s&7,
  // global chunk c = seg ^ (row&7)  (reader swizzle matches)
  const void* regP = d.reg_is_b ? d.Bt : d.A;
  const void* dP = d.reg_is_b ? d.A : d.Bt;
  const int regRowBase = d.reg_is_b ? colBase : rowBase;
  const int dRowBase = d.reg_is_b ? rowBase : colBase;

  const void* gR[4];
  const unsigned short* gD[4];
  unsigned short* lR[4];
  int so[4];
#pragma unroll
  for (int i = 0; i < 4; ++i) {
    int s = tid + i * 256;
    int row = s >> 3;
    int c = (s & 7) ^ (row & 7);
    size_t offR = (size_t)(regRowBase + row) * 1024 + c * 8;
    size_t offD = (size_t)(dRowBase + row) * 1024 + c * 8;
    gR[i] = d.reg_f32
                ? (const void*)((const float*)regP + offR)
                : (const void*)((const unsigned short*)regP + offR);
    gD[i] = (const unsigned short*)dP + offD;
    lR[i] = &Rs[s * 8];
    so[i] = s * 8;
  }

  // prologue: R(0) -> regs, D(0) -> Ds buf0
  float4 rf[4][2];
  uint4v rh[4];
  if (d.reg_f32) {
#pragma unroll
    for (int i = 0; i < 4; ++i) {
      rf[i][0] = *(const float4*)gR[i];
      rf[i][1] = *(const float4*)((const float*)gR[i] + 4);
    }
  } else {
#pragma unroll
    for (int i = 0; i < 4; ++i) rh[i] = *(const uint4v*)gR[i];
  }
#pragma unroll
  for (int i = 0; i < 4; ++i) gl2lds16(gD[i], &Ds[so[i]]);

  for (int kt = 0; kt < 16; ++kt) {
    const int cb = (kt & 1) * 8192;  // current D buffer (shorts)
    const int nbuf = 8192 - cb;
    __syncthreads();  // #1: prior-tile reads done; drains D(kt)+R(kt) loads
                      // (both issued at last iter's compute start -> hidden)

    // ds_write reg-staged tile kt (cvt_pk for fp32)
    if (d.reg_f32) {
#pragma unroll
      for (int i = 0; i < 4; ++i) {
        uint4v u;
        u[0] = pk2(rf[i][0].x, rf[i][0].y);
        u[1] = pk2(rf[i][0].z, rf[i][0].w);
        u[2] = pk2(rf[i][1].x, rf[i][1].y);
        u[3] = pk2(rf[i][1].z, rf[i][1].w);
        *(uint4v*)lR[i] = u;
      }
    } else {
#pragma unroll
      for (int i = 0; i < 4; ++i) *(uint4v*)lR[i] = rh[i];
    }
    __syncthreads();  // #2: Rs visible; vm queue empty -> cheap drain

    if (kt < 15) {  // issue next-tile loads at compute start
      const int ko = (kt + 1) * 64;
#pragma unroll
      for (int i = 0; i < 4; ++i) gl2lds16(gD[i] + ko, &Ds[nbuf + so[i]]);
      if (d.reg_f32) {
#pragma unroll
        for (int i = 0; i < 4; ++i) {
          rf[i][0] = *(const float4*)((const float*)gR[i] + ko);
          rf[i][1] = *(const float4*)((const float*)gR[i] + ko + 4);
        }
      } else {
#pragma unroll
        for (int i = 0; i < 4; ++i)
          rh[i] = *(const uint4v*)((const unsigned short*)gR[i] + ko);
      }
    }

    const unsigned short* At = d.reg_is_b ? &Ds[cb] : Rs;
    const unsigned short* Bt2 = d.reg_is_b ? Rs : &Ds[cb];
#pragma unroll
    for (int ks = 0; ks < 2; ++ks) {
      bf16x8 af[4], bfr[4];
#pragma unroll
      for (int mt = 0; mt < 4; ++mt) {
        int row = wm + mt * 16 + lr;
        int c = (ks * 4 + lg) ^ (row & 7);
        af[mt] = *(const bf16x8*)&At[row * 64 + c * 8];
      }
#pragma unroll
      for (int nt = 0; nt < 4; ++nt) {
        int row = wn + nt * 16 + lr;
        int c = (ks * 4 + lg) ^ (row & 7);
        bfr[nt] = *(const bf16x8*)&Bt2[row * 64 + c * 8];
      }
#pragma unroll
      for (int mt = 0; mt < 4; ++mt)
#pragma unroll
        for (int nt = 0; nt < 4; ++nt)
          acc[mt][nt] = __builtin_amdgcn_mfma_f32_16x16x32_bf16(
              af[mt], bfr[nt], acc[mt][nt], 0, 0, 0);
    }
  }

  // epilogue: C-layout col=lane&15, row=(lane>>4)*4+reg
#pragma unroll
  for (int mt = 0; mt < 4; ++mt)
#pragma unroll
    for (int nt = 0; nt < 4; ++nt) {
      int col = colBase + wn + nt * 16 + lr;
      float bcol = d.bias_row ? 0.f : d.bias[col];
#pragma unroll
      for (int r = 0; r < 4; ++r) {
        int row = rowBase + wm + mt * 16 + lg * 4 + r;
        float b = d.bias_row ? d.bias[row] : bcol;
        float val = (acc[mt][nt][r] + b) * d.scale;
        size_t idx = (size_t)row * (size_t)d.N + (size_t)col;
        if (OUT_F32)
          ((float*)d.C)[idx] = val;
        else
          ((unsigned short*)d.C)[idx] = f2bf(val);
      }
    }
}

// ---------------------------------------------------------------- attention
// (round-8 best: 78.5 us, no spill)  One block per (n, h, 128-row q-tile).
// 4 waves x 32 q-rows.  KT=64.  XCD-local placement; register-lean
// half-tile pipeline; in-register P; ones-MFMA row-sum; zero-C QK^T.
__global__ __launch_bounds__(256, 4) void attn_k(
    const unsigned short* __restrict__ qb,   // [8192][1024]
    const unsigned short* __restrict__ kb,   // [8192][1024]
    const unsigned short* __restrict__ vtb,  // [1024][8192] natural key order
    unsigned short* __restrict__ aob) {      // [8192][1024]
  __shared__ __attribute__((aligned(16))) unsigned short Ks[2 * 64 * 64];
  __shared__ __attribute__((aligned(16))) unsigned short Vts[2 * 64 * 64];

  const int tid = threadIdx.x;
  const int lane = tid & 63, wave = tid >> 6;
  const int lr = lane & 15, lg = lane >> 4;

  const int bid = blockIdx.x;
  const int xcd = bid & 7;
  const int idx = bid >> 3;
  const int qt = idx & 15;
  const int nh = (idx >> 4) * 8 + xcd;
  const int h = nh & 15, n = nh >> 4;
  const int q0 = qt * 128;

  // ---- stage Q tile (128x64 = 16KB) overlaying both K buffers
#pragma unroll
  for (int i = 0; i < 4; ++i) {
    int s = i * 256 + tid;
    int row = s >> 3;
    int c = (s & 7) ^ (row & 7);
    gl2lds16(qb + (((size_t)n * 2048 + q0 + row) << 10) + h * 64 + c * 8,
             &Ks[s * 8]);
  }
  __syncthreads();

  bf16x8 aq[2][2];
#pragma unroll
  for (int mt = 0; mt < 2; ++mt)
#pragma unroll
    for (int ks = 0; ks < 2; ++ks) {
      int row = wave * 32 + mt * 16 + lr;
      int c = (ks * 4 + lg) ^ (row & 7);
      aq[mt][ks] = *(const bf16x8*)&Ks[row * 64 + c * 8];
    }
  __syncthreads();  // Q reads done; Ks becomes K double-buffer

  const int a0 = lr * 64 + ((lg ^ (lr & 7)) * 8);
  const int a1 = lr * 64 + (((4 + lg) ^ (lr & 7)) * 8);
  const unsigned short* Kb0 = &Ks[a0];
  const unsigned short* Kb1 = &Ks[a1];
  const unsigned short* Vb0 = &Vts[a0];
  const unsigned short* Vb1 = &Vts[a1];

  const unsigned short* kg[2];
  const unsigned short* vg[2];
  int ldo[2];
#pragma unroll
  for (int i = 0; i < 2; ++i) {
    int s = i * 256 + tid;
    int row = s >> 3;
    int c = (s & 7) ^ (row & 7);
    kg[i] = kb + (((size_t)n * 2048 + row) << 10) + h * 64 + c * 8;
    vg[i] = vtb + (((size_t)(h * 64 + row)) << 13) + (size_t)n * 2048 + c * 8;
    ldo[i] = s * 8;
  }
#pragma unroll
  for (int i = 0; i < 2; ++i) {
    gl2lds16(kg[i], &Ks[ldo[i]]);
    gl2lds16(vg[i], &Vts[ldo[i]]);
    kg[i] += 64 * 1024;
    vg[i] += 64;
  }

  bf16x8 ones;
#pragma unroll
  for (int i = 0; i < 8; ++i) ones[i] = (__bf16)1.0f;
  const f32x4 fzero = {0.f, 0.f, 0.f, 0.f};

  f32x4 o_acc[2][4] = {};
  f32x4 o_sum[2] = {};

#pragma unroll 2
  for (int kt = 0; kt < 32; ++kt) {
    const int cb = (kt & 1) * 4096;
    const int nb = 4096 - cb;
    __syncthreads();

    if (kt < 31) {
#pragma unroll
      for (int i = 0; i < 2; ++i) {
        gl2lds16(kg[i], &Ks[nb + ldo[i]]);
        gl2lds16(vg[i], &Vts[nb + ldo[i]]);
        kg[i] += 64 * 1024;
        vg[i] += 64;
      }
    }

    f32x4 sA[2][2], sB[2][2];
    {
      bf16x8 k00 = *(const bf16x8*)(Kb0 + cb);
      bf16x8 k10 = *(const bf16x8*)(Kb1 + cb);
      bf16x8 k01 = *(const bf16x8*)(Kb0 + cb + 1024);
      bf16x8 k11 = *(const bf16x8*)(Kb1 + cb + 1024);
      __builtin_amdgcn_s_setprio(1);
#pragma unroll
      for (int mt = 0; mt < 2; ++mt) {
        f32x4 t0 = __builtin_amdgcn_mfma_f32_16x16x32_bf16(
            k00, aq[mt][0], fzero, 0, 0, 0);
        sA[mt][0] = __builtin_amdgcn_mfma_f32_16x16x32_bf16(
            k10, aq[mt][1], t0, 0, 0, 0);
        f32x4 t1 = __builtin_amdgcn_mfma_f32_16x16x32_bf16(
            k01, aq[mt][0], fzero, 0, 0, 0);
        sA[mt][1] = __builtin_amdgcn_mfma_f32_16x16x32_bf16(
            k11, aq[mt][1], t1, 0, 0, 0);
      }
      __builtin_amdgcn_s_setprio(0);
    }
    {
      bf16x8 k02 = *(const bf16x8*)(Kb0 + cb + 2048);
      bf16x8 k12 = *(const bf16x8*)(Kb1 + cb + 2048);
      bf16x8 k03 = *(const bf16x8*)(Kb0 + cb + 3072);
      bf16x8 k13 = *(const bf16x8*)(Kb1 + cb + 3072);
      __builtin_amdgcn_s_setprio(1);
#pragma unroll
      for (int mt = 0; mt < 2; ++mt) {
        f32x4 t0 = __builtin_amdgcn_mfma_f32_16x16x32_bf16(
            k02, aq[mt][0], fzero, 0, 0, 0);
        sB[mt][0] = __builtin_amdgcn_mfma_f32_16x16x32_bf16(
            k12, aq[mt][1], t0, 0, 0, 0);
        f32x4 t1 = __builtin_amdgcn_mfma_f32_16x16x32_bf16(
            k03, aq[mt][0], fzero, 0, 0, 0);
        sB[mt][1] = __builtin_amdgcn_mfma_f32_16x16x32_bf16(
            k13, aq[mt][1], t1, 0, 0, 0);
      }
      __builtin_amdgcn_s_setprio(0);
    }

    {
      bf16x8 bv0[4];
#pragma unroll
      for (int nt = 0; nt < 4; ++nt)
        bv0[nt] = *(const bf16x8*)(Vb0 + cb + nt * 1024);

      bf16x8 ap0[2];
#pragma unroll
      for (int mt = 0; mt < 2; ++mt) ap0[mt] = mk_ap(sA[mt][0], sA[mt][1]);

      __builtin_amdgcn_s_setprio(1);
#pragma unroll
      for (int mt = 0; mt < 2; ++mt) {
        o_sum[mt] = __builtin_amdgcn_mfma_f32_16x16x32_bf16(
            ap0[mt], ones, o_sum[mt], 0, 0, 0);
#pragma unroll
        for (int nt = 0; nt < 4; ++nt)
          o_acc[mt][nt] = __builtin_amdgcn_mfma_f32_16x16x32_bf16(
              ap0[mt], bv0[nt], o_acc[mt][nt], 0, 0, 0);
      }
      __builtin_amdgcn_s_setprio(0);
    }

    {
      bf16x8 bv1[4];
#pragma unroll
      for (int nt = 0; nt < 4; ++nt)
        bv1[nt] = *(const bf16x8*)(Vb1 + cb + nt * 1024);

      bf16x8 ap1[2];
#pragma unroll
      for (int mt = 0; mt < 2; ++mt) ap1[mt] = mk_ap(sB[mt][0], sB[mt][1]);

      __builtin_amdgcn_s_setprio(1);
#pragma unroll
      for (int mt = 0; mt < 2; ++mt) {
        o_sum[mt] = __builtin_amdgcn_mfma_f32_16x16x32_bf16(
            ap1[mt], ones, o_sum[mt], 0, 0, 0);
#pragma unroll
        for (int nt = 0; nt < 4; ++nt)
          o_acc[mt][nt] = __builtin_amdgcn_mfma_f32_16x16x32_bf16(
              ap1[mt], bv1[nt], o_acc[mt][nt], 0, 0, 0);
      }
      __builtin_amdgcn_s_setprio(0);
    }
  }

#pragma unroll
  for (int mt = 0; mt < 2; ++mt) {
#pragma unroll
    for (int r = 0; r < 4; ++r) {
      float inv = 1.0f / o_sum[mt][r];
      int row_l = q0 + wave * 32 + mt * 16 + lg * 4 + r;
      size_t base = (((size_t)n * 2048 + row_l) << 10) + h * 64;
#pragma unroll
      for (int nt = 0; nt < 4; ++nt)
        aob[base + nt * 16 + lr] = f2bf(o_acc[mt][nt][r] * inv);
    }
  }
}

// ---------------------------------------------------------------- launch
extern "C" void kernel_launch(void* const* d_in, const int* in_sizes, int n_in,
                              void* d_out, int out_size, void* d_ws,
                              size_t ws_size, hipStream_t stream) {
  const float* Q = (const float*)d_in[0];
  const float* K = (const float*)d_in[1];
  const float* V = (const float*)d_in[2];
  const float* Wq = (const float*)d_in[3];
  const float* bq = (const float*)d_in[4];
  const float* Wk = (const float*)d_in[5];
  const float* bk = (const float*)d_in[6];
  const float* Wv = (const float*)d_in[7];
  const float* bv = (const float*)d_in[8];
  const float* Wo = (const float*)d_in[9];
  const float* bo = (const float*)d_in[10];

  const size_t S = (size_t)8192 * 1024;
  const size_t W = (size_t)1024 * 1024;
  unsigned short* ws = (unsigned short*)d_ws;
  unsigned short* aob = ws;  // attention output (bf16)
  unsigned short* qbuf = ws + 3 * S;
  unsigned short* kbuf = ws + 4 * S;
  unsigned short* vtbuf = ws + 5 * S;
  unsigned short* Wqb = ws + 6 * S;
  unsigned short* Wkb = Wqb + W;
  unsigned short* Wvb = Wqb + 2 * W;
  unsigned short* Wob = Wqb + 3 * W;

  CvtArgs cw;
  cw.src[0] = Wq; cw.dst[0] = Wqb;
  cw.src[1] = Wk; cw.dst[1] = Wkb;
  cw.src[2] = Wv; cw.dst[2] = Wvb;
  cw.src[3] = Wo; cw.dst[3] = Wob;
  cvt_w_k<<<dim3(1024, 4), 256, 0, stream>>>(cw);

  // fused QKV projections (activations fp32, reg-staged with T14 split):
  //   g0: q = (Q Wq^T + bq)*log2e/8            [8192x1024]  reg=A fp32
  //   g1: k =  K Wk^T + bk                     [8192x1024]  reg=A fp32
  //   g2: v^T = Wvb V^T + bv (natural order)   [1024x8192]  reg=B fp32
  GemmPack3 pp;
  pp.g[0] = {Q, Wqb, bq, qbuf, 1024, 3, LOG2E_OVER_SQRTD, 0, 0, 0, 1};
  pp.g[1] = {K, Wkb, bk, kbuf, 1024, 3, 1.0f, 0, 0, 0, 1};
  pp.g[2] = {Wvb, V, bv, vtbuf, 8192, 6, 1.0f, 1, 0, 1, 1};
  gemm_multi_k<false><<<1536, 256, 0, stream>>>(pp);

  attn_k<<<1024, 256, 0, stream>>>(qbuf, kbuf, vtbuf, aob);

  // out = AO Wo^T + bo  (fp32; reg=A bf16 copy, D=Wob dbuf)
  GemmPack3 po;
  po.g[0] = {aob, Wob, bo, d_out, 1024, 3, 1.0f, 0, 0, 0, 0};
  po.g[1] = po.g[0];
  po.g[2] = po.g[0];
  gemm_multi_k<true><<<512, 256, 0, stream>>>(po);
}

// Round 14
// 318.111 us; speedup vs baseline: 1.2405x; 1.1965x over previous
//
#include <hip/hip_runtime.h>
#include <cstdint>
#include <cstddef>

// N=4, L=2048, E=1024, H=16, D=64.  Token rows M = N*L = 8192.
// Pipeline (verified best configuration, R6 = 330.9 us):
// cvt fp32->bf16 (single merged launch), fused QKV projection GEMM (one
// 1536-block launch, BK=64, single-buffered m97 structure, chunked-XCD
// remap, (256,2)), no-max flash attention (4 waves, in-register P via
// swapped QK^T + permlane swaps, double-buffered K/V, XCD-local head
// placement, ones-MFMA row-sum, zero-C QK^T, register-lean half-tile
// pipeline), output GEMM (fp32 out).
//
// NOTE: do NOT raise the GEMM __launch_bounds__ min-waves arg.  (256,4)
// caps VGPR at 64 (< live state) -> heavy spill; spill traffic shares the
// vmcnt queue with global_load_lds and the barrier-drain interaction
// miscompiles: first launch correct, graph replays diverge (R13).
// (256,2) verified correct and fastest; (256,3) correct, +2us.

typedef __bf16 bf16x8 __attribute__((ext_vector_type(8)));
typedef __bf16 bf16x4 __attribute__((ext_vector_type(4)));
typedef __bf16 bf16x2 __attribute__((ext_vector_type(2)));
typedef float f32x4 __attribute__((ext_vector_type(4)));
typedef float f32x2 __attribute__((ext_vector_type(2)));
typedef unsigned int uint2v __attribute__((ext_vector_type(2)));
typedef unsigned int uint4v __attribute__((ext_vector_type(4)));

#define LOG2E_OVER_SQRTD 0.18033688011112042f  // log2(e)/8, folded into q

__device__ __forceinline__ unsigned short f2bf(float f) {
  unsigned int u = __builtin_bit_cast(unsigned int, f);
  u = (u + 0x7fffu + ((u >> 16) & 1u)) >> 16;  // RNE
  return (unsigned short)u;
}

__device__ __forceinline__ unsigned int pk2(float a, float b) {
  f32x2 t = {a, b};
  bf16x2 h = __builtin_convertvector(t, bf16x2);  // v_cvt_pk_bf16_f32 (RNE)
  return __builtin_bit_cast(unsigned int, h);
}

// async 16B global->LDS
__device__ __forceinline__ void gl2lds16(const void* g, void* l) {
  __builtin_amdgcn_global_load_lds(
      (__attribute__((address_space(1))) unsigned int*)g,
      (__attribute__((address_space(3))) unsigned int*)l, 16, 0, 0);
}

// softmax half-tile: S^T frags (two 16-row key blocks) -> PV A-fragment.
// lane (g'=lg, q=lr) holds P^T[k][q]; permlane32+permlane16 swaps
// redistribute packed bf16 pairs into A-frag order (keys 8g..8g+7).
__device__ __forceinline__ bf16x8 mk_ap(f32x4 sA, f32x4 sB) {
  float peA[4], peB[4];
#pragma unroll
  for (int r = 0; r < 4; ++r) {
    peA[r] = __builtin_amdgcn_exp2f(sA[r]);
    peB[r] = __builtin_amdgcn_exp2f(sB[r]);
  }
  unsigned int x00 = pk2(peA[0], peA[1]);
  unsigned int x01 = pk2(peA[2], peA[3]);
  unsigned int x10 = pk2(peB[0], peB[1]);
  unsigned int x11 = pk2(peB[2], peB[3]);
  uint2v s0 = __builtin_amdgcn_permlane32_swap(x00, x10, false, false);
  uint2v t0 = __builtin_amdgcn_permlane16_swap(s0[0], s0[1], false, false);
  uint2v s1 = __builtin_amdgcn_permlane32_swap(x01, x11, false, false);
  uint2v t1 = __builtin_amdgcn_permlane16_swap(s1[0], s1[1], false, false);
  uint4v u;
  u[0] = t0[0];  // k 8g+0,1
  u[1] = t1[0];  // k 8g+2,3
  u[2] = t0[1];  // k 8g+4,5
  u[3] = t1[1];  // k 8g+6,7
  return __builtin_bit_cast(bf16x8, u);
}

// ---------------------------------------------------------------- cvt kernel
// Single launch: regions 0-2 = activations (8192 blocks each), 3-6 = weights
// (1024 blocks each).  Grid = 3*8192 + 4*1024 = 28672.
struct CvtArgs {
  const float* src[7];
  unsigned short* dst[7];
};
__global__ __launch_bounds__(256) void cvt_all_k(CvtArgs a) {
  int bid = blockIdx.x;
  int which, x;
  if (bid < 24576) {
    which = bid >> 13;
    x = bid & 8191;
  } else {
    int r = bid - 24576;
    which = 3 + (r >> 10);
    x = r & 1023;
  }
  const float* s = a.src[which];
  unsigned short* d = a.dst[which];
  size_t i = ((size_t)x * 256 + threadIdx.x) * 4;
  float4 v = *(const float4*)(s + i);
  ushort4 o;
  o.x = f2bf(v.x); o.y = f2bf(v.y); o.z = f2bf(v.z); o.w = f2bf(v.w);
  *(ushort4*)(d + i) = o;
}

// ---------------------------------------------------------------- GEMM
// C[M][N] = A[M][1024] @ Bt[N][1024]^T, bf16 in, fp32 acc.  128x128 tile,
// BK=64 (16 K-iters), 4 waves each 64x64.  Multi-GEMM: blockIdx.x>>9 picks
// the descriptor (512 blocks per GEMM).  Single-buffered m97 structure
// (proven fastest of all variants tried: dbuf/fused-cvt/T14 all slower).
// Chunked-XCD remap (nbx_shift==3 GEMMs only): keeps each XCD on 8
// contiguous by (2 MB A, fetched once) x all 8 B-panels -- L2-resident.
struct GemmDesc {
  const unsigned short* A;
  const unsigned short* Bt;
  const float* bias;
  void* C;
  int N;          // C column count / row stride
  int nbx_shift;  // log2(N/128)
  float scale;
  int bias_row;   // bias indexed by row instead of col
  int permc;      // store cols permuted: col' = 4*(col&15) + ((col>>4)&3)
};
struct GemmPack3 {
  GemmDesc g[3];
};

template <bool OUT_F32>
__global__ __launch_bounds__(256, 2) void gemm_multi_k(GemmPack3 p) {
  __shared__ __attribute__((aligned(16))) unsigned short As[128 * 64];
  __shared__ __attribute__((aligned(16))) unsigned short Bs[128 * 64];
  const GemmDesc d = p.g[blockIdx.x >> 9];
  int t = blockIdx.x & 511;
  if (d.nbx_shift == 3) t = ((t & 7) << 6) | (t >> 3);  // chunked XCD remap
  const int bx = t & ((1 << d.nbx_shift) - 1);
  const int by = t >> d.nbx_shift;

  const int tid = threadIdx.x;
  const int lane = tid & 63, wave = tid >> 6;
  const int lr = lane & 15, lg = lane >> 4;
  const int rowBase = by * 128;
  const int colBase = bx * 128;
  const int wm = (wave & 1) * 64, wn = (wave >> 1) * 64;

  f32x4 acc[4][4] = {};

  // staging: 4 slots/thread/matrix; slot s -> row=s>>3, seg t=s&7,
  // global chunk c = t ^ (row&7)  (reader swizzle matches)
  const unsigned short* gA[4];
  const unsigned short* gB[4];
  unsigned short* lA[4];
  unsigned short* lB[4];
#pragma unroll
  for (int i = 0; i < 4; ++i) {
    int s = tid + i * 256;
    int row = s >> 3;
    int c = (s & 7) ^ (row & 7);
    gA[i] = d.A + (size_t)(rowBase + row) * 1024 + c * 8;
    gB[i] = d.Bt + (size_t)(colBase + row) * 1024 + c * 8;
    lA[i] = &As[s * 8];
    lB[i] = &Bs[s * 8];
  }

  for (int kt = 0; kt < 16; ++kt) {
    const int ko = kt * 64;
#pragma unroll
    for (int i = 0; i < 4; ++i) {
      gl2lds16(gA[i] + ko, lA[i]);
      gl2lds16(gB[i] + ko, lB[i]);
    }
    __syncthreads();  // drains vmcnt before barrier (m97 structure)

#pragma unroll
    for (int ks = 0; ks < 2; ++ks) {
      bf16x8 af[4], bfr[4];
#pragma unroll
      for (int mt = 0; mt < 4; ++mt) {
        int row = wm + mt * 16 + lr;
        int c = (ks * 4 + lg) ^ (row & 7);
        af[mt] = *(const bf16x8*)&As[row * 64 + c * 8];
      }
#pragma unroll
      for (int nt = 0; nt < 4; ++nt) {
        int row = wn + nt * 16 + lr;
        int c = (ks * 4 + lg) ^ (row & 7);
        bfr[nt] = *(const bf16x8*)&Bs[row * 64 + c * 8];
      }
#pragma unroll
      for (int mt = 0; mt < 4; ++mt)
#pragma unroll
        for (int nt = 0; nt < 4; ++nt)
          acc[mt][nt] = __builtin_amdgcn_mfma_f32_16x16x32_bf16(
              af[mt], bfr[nt], acc[mt][nt], 0, 0, 0);
    }
    __syncthreads();  // waves done reading before restage
  }

  // epilogue: C-layout col=lane&15, row=(lane>>4)*4+reg
#pragma unroll
  for (int mt = 0; mt < 4; ++mt)
#pragma unroll
    for (int nt = 0; nt < 4; ++nt) {
      int col = colBase + wn + nt * 16 + lr;
      int colStore = d.permc ? (colBase + wn + lr * 4 + nt) : col;
      float bcol = d.bias_row ? 0.f : d.bias[col];
#pragma unroll
      for (int r = 0; r < 4; ++r) {
        int row = rowBase + wm + mt * 16 + lg * 4 + r;
        float b = d.bias_row ? d.bias[row] : bcol;
        float val = (acc[mt][nt][r] + b) * d.scale;
        size_t idx = (size_t)row * (size_t)d.N + (size_t)colStore;
        if (OUT_F32)
          ((float*)d.C)[idx] = val;
        else
          ((unsigned short*)d.C)[idx] = f2bf(val);
      }
    }
}

// ---------------------------------------------------------------- attention
// (best measured: 78.5-79.2 us, no spill)  One block per (n, h, 128-row
// q-tile).  4 waves x 32 q-rows.  KT=64.  XCD-local placement: all 16
// q-tiles of one (n,h) land on the SAME XCD -> K/V panels L2-resident.
// Register-lean half-tile pipeline: K-frags read per half and released;
// S0 -> S1(issue) -> bv0 reads -> softmax(S0) [overlaps S1 exec + bv0
// latency] -> PV0 -> bv1 reads -> softmax(S1) [overlaps PV0] -> PV1.
__global__ __launch_bounds__(256, 4) void attn_k(
    const unsigned short* __restrict__ qb,   // [8192][1024]
    const unsigned short* __restrict__ kb,   // [8192][1024]
    const unsigned short* __restrict__ vtb,  // [1024][8192] natural key order
    unsigned short* __restrict__ aob) {      // [8192][1024]
  __shared__ __attribute__((aligned(16))) unsigned short Ks[2 * 64 * 64];
  __shared__ __attribute__((aligned(16))) unsigned short Vts[2 * 64 * 64];

  const int tid = threadIdx.x;
  const int lane = tid & 63, wave = tid >> 6;
  const int lr = lane & 15, lg = lane >> 4;

  // XCD-local swizzle: xcd = bid&7 (dispatch round-robin), 16 q-tiles of
  // each nh stay on one XCD.  Bijective: nh = (idx>>4)*8 + xcd in [0,64).
  const int bid = blockIdx.x;
  const int xcd = bid & 7;
  const int idx = bid >> 3;
  const int qt = idx & 15;
  const int nh = (idx >> 4) * 8 + xcd;
  const int h = nh & 15, n = nh >> 4;
  const int q0 = qt * 128;

  // ---- stage Q tile (128x64 = 16KB) overlaying both K buffers
#pragma unroll
  for (int i = 0; i < 4; ++i) {
    int s = i * 256 + tid;
    int row = s >> 3;
    int c = (s & 7) ^ (row & 7);
    gl2lds16(qb + (((size_t)n * 2048 + q0 + row) << 10) + h * 64 + c * 8,
             &Ks[s * 8]);
  }
  __syncthreads();

  bf16x8 aq[2][2];
#pragma unroll
  for (int mt = 0; mt < 2; ++mt)
#pragma unroll
    for (int ks = 0; ks < 2; ++ks) {
      int row = wave * 32 + mt * 16 + lr;
      int c = (ks * 4 + lg) ^ (row & 7);
      aq[mt][ks] = *(const bf16x8*)&Ks[row * 64 + c * 8];
    }
  __syncthreads();  // Q reads done; Ks becomes K double-buffer

  // per-lane LDS read bases: index = nt*1024 + lr*64 + c(ks)*8 (+cb)
  const int a0 = lr * 64 + ((lg ^ (lr & 7)) * 8);
  const int a1 = lr * 64 + (((4 + lg) ^ (lr & 7)) * 8);
  const unsigned short* Kb0 = &Ks[a0];
  const unsigned short* Kb1 = &Ks[a1];
  const unsigned short* Vb0 = &Vts[a0];
  const unsigned short* Vb1 = &Vts[a1];

  // staging addresses fixed per thread; advance by one tile per iteration
  const unsigned short* kg[2];
  const unsigned short* vg[2];
  int ldo[2];
#pragma unroll
  for (int i = 0; i < 2; ++i) {
    int s = i * 256 + tid;
    int row = s >> 3;
    int c = (s & 7) ^ (row & 7);
    kg[i] = kb + (((size_t)n * 2048 + row) << 10) + h * 64 + c * 8;
    vg[i] = vtb + (((size_t)(h * 64 + row)) << 13) + (size_t)n * 2048 + c * 8;
    ldo[i] = s * 8;
  }
  // stage k-tile 0 into buffer 0
#pragma unroll
  for (int i = 0; i < 2; ++i) {
    gl2lds16(kg[i], &Ks[ldo[i]]);
    gl2lds16(vg[i], &Vts[ldo[i]]);
    kg[i] += 64 * 1024;
    vg[i] += 64;
  }

  bf16x8 ones;
#pragma unroll
  for (int i = 0; i < 8; ++i) ones[i] = (__bf16)1.0f;
  const f32x4 fzero = {0.f, 0.f, 0.f, 0.f};

  f32x4 o_acc[2][4] = {};
  f32x4 o_sum[2] = {};

#pragma unroll 2
  for (int kt = 0; kt < 32; ++kt) {
    const int cb = (kt & 1) * 4096;  // current buffer base (shorts)
    const int nb = 4096 - cb;        // next buffer base
    __syncthreads();  // buf[cur] staged; prior reads of buf[next] complete

    if (kt < 31) {  // prefetch next tile before compute (loads overlap MFMA)
#pragma unroll
      for (int i = 0; i < 2; ++i) {
        gl2lds16(kg[i], &Ks[nb + ldo[i]]);
        gl2lds16(vg[i], &Vts[nb + ldo[i]]);
        kg[i] += 64 * 1024;
        vg[i] += 64;
      }
    }

    f32x4 sA[2][2], sB[2][2];
    // S half0: keys 0..31; K-frags scoped so regs release after use
    {
      bf16x8 k00 = *(const bf16x8*)(Kb0 + cb);
      bf16x8 k10 = *(const bf16x8*)(Kb1 + cb);
      bf16x8 k01 = *(const bf16x8*)(Kb0 + cb + 1024);
      bf16x8 k11 = *(const bf16x8*)(Kb1 + cb + 1024);
      __builtin_amdgcn_s_setprio(1);
#pragma unroll
      for (int mt = 0; mt < 2; ++mt) {
        f32x4 t0 = __builtin_amdgcn_mfma_f32_16x16x32_bf16(
            k00, aq[mt][0], fzero, 0, 0, 0);
        sA[mt][0] = __builtin_amdgcn_mfma_f32_16x16x32_bf16(
            k10, aq[mt][1], t0, 0, 0, 0);
        f32x4 t1 = __builtin_amdgcn_mfma_f32_16x16x32_bf16(
            k01, aq[mt][0], fzero, 0, 0, 0);
        sA[mt][1] = __builtin_amdgcn_mfma_f32_16x16x32_bf16(
            k11, aq[mt][1], t1, 0, 0, 0);
      }
      __builtin_amdgcn_s_setprio(0);
    }
    // S half1: keys 32..63
    {
      bf16x8 k02 = *(const bf16x8*)(Kb0 + cb + 2048);
      bf16x8 k12 = *(const bf16x8*)(Kb1 + cb + 2048);
      bf16x8 k03 = *(const bf16x8*)(Kb0 + cb + 3072);
      bf16x8 k13 = *(const bf16x8*)(Kb1 + cb + 3072);
      __builtin_amdgcn_s_setprio(1);
#pragma unroll
      for (int mt = 0; mt < 2; ++mt) {
        f32x4 t0 = __builtin_amdgcn_mfma_f32_16x16x32_bf16(
            k02, aq[mt][0], fzero, 0, 0, 0);
        sB[mt][0] = __builtin_amdgcn_mfma_f32_16x16x32_bf16(
            k12, aq[mt][1], t0, 0, 0, 0);
        f32x4 t1 = __builtin_amdgcn_mfma_f32_16x16x32_bf16(
            k03, aq[mt][0], fzero, 0, 0, 0);
        sB[mt][1] = __builtin_amdgcn_mfma_f32_16x16x32_bf16(
            k13, aq[mt][1], t1, 0, 0, 0);
      }
      __builtin_amdgcn_s_setprio(0);
    }

    // V half0 reads (keys 0..31; latency hides under softmax half0)
    {
      bf16x8 bv0[4];
#pragma unroll
      for (int nt = 0; nt < 4; ++nt)
        bv0[nt] = *(const bf16x8*)(Vb0 + cb + nt * 1024);

      // softmax half0 (VALU; overlaps S-half1 MFMA exec + bv0 ds latency)
      bf16x8 ap0[2];
#pragma unroll
      for (int mt = 0; mt < 2; ++mt) ap0[mt] = mk_ap(sA[mt][0], sA[mt][1]);

      // PV half0 + row-sum
      __builtin_amdgcn_s_setprio(1);
#pragma unroll
      for (int mt = 0; mt < 2; ++mt) {
        o_sum[mt] = __builtin_amdgcn_mfma_f32_16x16x32_bf16(
            ap0[mt], ones, o_sum[mt], 0, 0, 0);
#pragma unroll
        for (int nt = 0; nt < 4; ++nt)
          o_acc[mt][nt] = __builtin_amdgcn_mfma_f32_16x16x32_bf16(
              ap0[mt], bv0[nt], o_acc[mt][nt], 0, 0, 0);
      }
      __builtin_amdgcn_s_setprio(0);
    }

    // V half1 reads + softmax half1 (overlaps PV half0 exec)
    {
      bf16x8 bv1[4];
#pragma unroll
      for (int nt = 0; nt < 4; ++nt)
        bv1[nt] = *(const bf16x8*)(Vb1 + cb + nt * 1024);

      bf16x8 ap1[2];
#pragma unroll
      for (int mt = 0; mt < 2; ++mt) ap1[mt] = mk_ap(sB[mt][0], sB[mt][1]);

      // PV half1 + row-sum
      __builtin_amdgcn_s_setprio(1);
#pragma unroll
      for (int mt = 0; mt < 2; ++mt) {
        o_sum[mt] = __builtin_amdgcn_mfma_f32_16x16x32_bf16(
            ap1[mt], ones, o_sum[mt], 0, 0, 0);
#pragma unroll
        for (int nt = 0; nt < 4; ++nt)
          o_acc[mt][nt] = __builtin_amdgcn_mfma_f32_16x16x32_bf16(
              ap1[mt], bv1[nt], o_acc[mt][nt], 0, 0, 0);
      }
      __builtin_amdgcn_s_setprio(0);
    }
  }

  // epilogue: O C-layout col=d=lane&15, row=q=(lane>>4)*4+r.
  // o_sum[mt][r] is the full row-sum for this lane's O-row already.
#pragma unroll
  for (int mt = 0; mt < 2; ++mt) {
#pragma unroll
    for (int r = 0; r < 4; ++r) {
      float inv = 1.0f / o_sum[mt][r];
      int row_l = q0 + wave * 32 + mt * 16 + lg * 4 + r;
      size_t base = (((size_t)n * 2048 + row_l) << 10) + h * 64;
#pragma unroll
      for (int nt = 0; nt < 4; ++nt)
        aob[base + nt * 16 + lr] = f2bf(o_acc[mt][nt][r] * inv);
    }
  }
}

// ---------------------------------------------------------------- launch
extern "C" void kernel_launch(void* const* d_in, const int* in_sizes, int n_in,
                              void* d_out, int out_size, void* d_ws,
                              size_t ws_size, hipStream_t stream) {
  const float* Q = (const float*)d_in[0];
  const float* K = (const float*)d_in[1];
  const float* V = (const float*)d_in[2];
  const float* Wq = (const float*)d_in[3];
  const float* bq = (const float*)d_in[4];
  const float* Wk = (const float*)d_in[5];
  const float* bk = (const float*)d_in[6];
  const float* Wv = (const float*)d_in[7];
  const float* bv = (const float*)d_in[8];
  const float* Wo = (const float*)d_in[9];
  const float* bo = (const float*)d_in[10];

  const size_t S = (size_t)8192 * 1024;
  const size_t W = (size_t)1024 * 1024;
  unsigned short* ws = (unsigned short*)d_ws;
  unsigned short* Qbf = ws;  // dead after q-proj; reused as attention output
  unsigned short* Kbf = ws + S;
  unsigned short* Vbf = ws + 2 * S;
  unsigned short* qbuf = ws + 3 * S;
  unsigned short* kbuf = ws + 4 * S;
  unsigned short* vtbuf = ws + 5 * S;
  unsigned short* Wqb = ws + 6 * S;
  unsigned short* Wkb = Wqb + W;
  unsigned short* Wvb = Wqb + 2 * W;
  unsigned short* Wob = Wqb + 3 * W;
  unsigned short* aob = Qbf;

  CvtArgs cv;
  cv.src[0] = Q;  cv.dst[0] = Qbf;
  cv.src[1] = K;  cv.dst[1] = Kbf;
  cv.src[2] = V;  cv.dst[2] = Vbf;
  cv.src[3] = Wq; cv.dst[3] = Wqb;
  cv.src[4] = Wk; cv.dst[4] = Wkb;
  cv.src[5] = Wv; cv.dst[5] = Wvb;
  cv.src[6] = Wo; cv.dst[6] = Wob;
  cvt_all_k<<<28672, 256, 0, stream>>>(cv);

  // fused QKV projections: g0: q = (Qbf Wq^T + bq)*log2e/8  [8192x1024]
  //                        g1: k =  Kbf Wk^T + bk           [8192x1024]
  //                        g2: v^T = Wvb Vbf^T + bv (natural order) [1024x8192]
  GemmPack3 pp;
  pp.g[0] = {Qbf, Wqb, bq, qbuf, 1024, 3, LOG2E_OVER_SQRTD, 0, 0};
  pp.g[1] = {Kbf, Wkb, bk, kbuf, 1024, 3, 1.0f, 0, 0};
  pp.g[2] = {Wvb, Vbf, bv, vtbuf, 8192, 6, 1.0f, 1, 0};
  gemm_multi_k<false><<<1536, 256, 0, stream>>>(pp);

  attn_k<<<1024, 256, 0, stream>>>(qbuf, kbuf, vtbuf, aob);

  // out = AO Wo^T + bo  (fp32)
  GemmPack3 po;
  po.g[0] = {aob, Wob, bo, d_out, 1024, 3, 1.0f, 0, 0};
  po.g[1] = po.g[0];
  po.g[2] = po.g[0];
  gemm_multi_k<true><<<512, 256, 0, stream>>>(po);
}